// Round 10
// baseline (155.289 us; speedup 1.0000x reference)
//
#include <hip/hip_runtime.h>

#define NN 100000
#define D  128
#define NE 1600000

#define NBK2 782          // ceil(NN/128) buckets (dst>>7), 128 nodes each
#define CAP2 2816         // slots per bucket (mean 2048, sigma ~45)
#define EPB  8192         // edges per fill block
#define NFB  196          // ceil(NE/EPB)
#define ENTCAP 2048       // per-half-bucket entry cap

typedef __bf16 bf16x8 __attribute__((ext_vector_type(8)));
typedef __bf16 bf16x4 __attribute__((ext_vector_type(4)));
typedef float  f32x4  __attribute__((ext_vector_type(4)));

// ---------------------------------------------------------------------------
// init: w1t/w2t = bf16(W^T), gcur = 0   (must precede fill2x's atomics)
// ---------------------------------------------------------------------------
__global__ __launch_bounds__(256)
void init_kernel(const float* __restrict__ W1, const float* __restrict__ W2,
                 __bf16* __restrict__ w1t, __bf16* __restrict__ w2t,
                 int* __restrict__ gcur) {
    const int bid = blockIdx.x;
    const int tid = threadIdx.x;
    if (bid < 128) {
        int i = bid * 256 + tid;                 // < 32768
        if (i < 16384) {
            int c = i >> 7, k = i & 127;
            w1t[i] = (__bf16)W1[k * 128 + c];
        } else {
            int j = i - 16384;
            int c = j >> 7, k = j & 127;
            w2t[j] = (__bf16)W2[k * 128 + c];
        }
    } else {
        int i = (bid - 128) * 256 + tid;
        if (i < NBK2) gcur[i] = 0;
    }
}

// ---------------------------------------------------------------------------
// fill2x (unchanged from R9): LDS-binned coalesced bucket-CSR fill with
// fused x->bf16 conversion. Entry = (dst&127)<<17 | src.
// ---------------------------------------------------------------------------
__global__ __launch_bounds__(512)
void fill2x_kernel(const float* __restrict__ x, const int* __restrict__ ei,
                   int* __restrict__ gcur, __bf16* __restrict__ xb,
                   int* __restrict__ bedge) {
    __shared__ int            stage[EPB];    // 32 KB
    __shared__ unsigned short bid16[EPB];    // 16 KB
    __shared__ int            lofs[NBK2];
    __shared__ int            lpos[NBK2];
    __shared__ int            gbase[NBK2];
    __shared__ int            ssum[512];
    __shared__ int            tot;

    const int tid = threadIdx.x;
    const int e0  = blockIdx.x * EPB;

    for (int b = tid; b < NBK2; b += 512) lpos[b] = 0;
    __syncthreads();

    int eb[16], epk[16];
    #pragma unroll 16
    for (int k = 0; k < 16; ++k) {
        int e = e0 + k * 512 + tid;
        eb[k] = -1;
        if (e < NE) {
            int s = ei[e];
            int d = ei[NE + e];
            if ((unsigned)s < NN && (unsigned)d < NN) {
                eb[k]  = d >> 7;
                epk[k] = ((d & 127) << 17) | s;
                atomicAdd(&lpos[eb[k]], 1);
            }
        }
    }

    // fused xprep: streaming bf16 conversion, overlaps the barrier stalls
    for (int i = blockIdx.x * 512 + tid; i < NN * 32; i += NFB * 512) {
        float4 v = reinterpret_cast<const float4*>(x)[i];
        bf16x4 o = {(__bf16)v.x, (__bf16)v.y, (__bf16)v.z, (__bf16)v.w};
        reinterpret_cast<bf16x4*>(xb)[i] = o;
    }
    __syncthreads();

    int t2 = tid * 2;
    int c0 = (t2 < NBK2) ? lpos[t2] : 0;
    int c1 = (t2 + 1 < NBK2) ? lpos[t2 + 1] : 0;
    ssum[tid] = c0 + c1;
    __syncthreads();
    for (int off = 1; off < 512; off <<= 1) {
        int v = (tid >= off) ? ssum[tid - off] : 0;
        __syncthreads();
        ssum[tid] += v;
        __syncthreads();
    }
    int excl = ssum[tid] - (c0 + c1);
    if (t2 < NBK2) {
        lofs[t2] = excl;
        lpos[t2] = excl;
        if (c0) gbase[t2] = atomicAdd(&gcur[t2], c0);
    }
    if (t2 + 1 < NBK2) {
        lofs[t2 + 1] = excl + c0;
        lpos[t2 + 1] = excl + c0;
        if (c1) gbase[t2 + 1] = atomicAdd(&gcur[t2 + 1], c1);
    }
    if (tid == 511) tot = ssum[511];
    __syncthreads();

    #pragma unroll 16
    for (int k = 0; k < 16; ++k) {
        if (eb[k] >= 0) {
            int r = atomicAdd(&lpos[eb[k]], 1);
            stage[r] = epk[k];
            bid16[r] = (unsigned short)eb[k];
        }
    }
    __syncthreads();

    int T = tot;
    for (int i = tid; i < T; i += 512) {
        int b   = bid16[i];
        int pos = gbase[b] + (i - lofs[b]);
        if (pos < CAP2) bedge[b * CAP2 + pos] = stage[i];
    }
}

// ---------------------------------------------------------------------------
// gather_mlp: gather3's structure (2 blocks/bucket, 256 thr) with the 64-row
// MLP fused on the tail. h rows go to a 16 KB swizzled LDS tile (not global);
// then out = relu(h@W1+b1)@W2+b2 with B-frags from L2-resident w1t/w2t.
// LDS ~25.6 KB -> ~5-6 blocks/CU; no cross-block dependencies.
// ---------------------------------------------------------------------------
__global__ __launch_bounds__(256)
void gather_mlp_kernel(const __bf16* __restrict__ xb, const int* __restrict__ gcur,
                       const int* __restrict__ bedge,
                       const __bf16* __restrict__ w1t,
                       const __bf16* __restrict__ w2t,
                       const float* __restrict__ b1,
                       const float* __restrict__ b2,
                       float* __restrict__ out) {
    __shared__ int ent[ENTCAP];                               // 8 KB
    __shared__ int c64[64], ofs[65], cur[64], scn[64];
    __shared__ __align__(16) unsigned char sh_h[64 * 256];    // 16 KB swizzled

    const int b    = blockIdx.x >> 1;
    const int half = blockIdx.x & 1;
    const int tid  = threadIdx.x;

    int cnt = gcur[b]; if (cnt > CAP2) cnt = CAP2;
    const int base = b * CAP2;

    // --- counting sort of this half's entries by node ---
    if (tid < 64) c64[tid] = 0;
    __syncthreads();

    for (int i = tid; i < cnt; i += 256) {
        int v  = bedge[base + i];
        int dl = v >> 17;
        if ((dl >> 6) == half) atomicAdd(&c64[dl & 63], 1);
    }
    __syncthreads();

    if (tid < 64) scn[tid] = c64[tid];
    __syncthreads();
    #pragma unroll
    for (int off = 1; off < 64; off <<= 1) {
        int v = (tid >= off && tid < 64) ? scn[tid - off] : 0;
        __syncthreads();
        if (tid < 64) scn[tid] += v;
        __syncthreads();
    }
    if (tid < 64) {
        ofs[tid + 1] = scn[tid];
        if (tid == 0) ofs[0] = 0;
        cur[tid] = scn[tid] - c64[tid];
    }
    __syncthreads();

    for (int i = tid; i < cnt; i += 256) {
        int v  = bedge[base + i];
        int dl = v >> 17;
        if ((dl >> 6) == half) {
            int r = atomicAdd(&cur[dl & 63], 1);
            if (r < ENTCAP) ent[r] = v & 0x1FFFF;
        }
    }
    __syncthreads();

    // --- gather h rows into swizzled LDS (zeros for invalid nodes) ---
    const int wave   = tid >> 6;
    const int lane   = tid & 63;
    const int half32 = lane >> 5;
    const int l31    = lane & 31;
    const bf16x4* xv4 = reinterpret_cast<const bf16x4*>(xb);

    for (int q = wave; q < 64; q += 4) {
        int node = b * 128 + half * 64 + q;
        float a0 = 0.f, a1 = 0.f, a2 = 0.f, a3 = 0.f;
        if (node < NN) {
            int beg = ofs[q], end = ofs[q + 1];
            if (beg > ENTCAP) beg = ENTCAP;
            if (end > ENTCAP) end = ENTCAP;
            float b0 = 0.f, b1f = 0.f, b2f = 0.f, b3f = 0.f;
            int j = beg;
            for (; j + 4 <= end; j += 4) {
                int s0 = ent[j + half32];
                int s1 = ent[j + 2 + half32];
                bf16x4 v0 = xv4[(size_t)s0 * 32 + l31];
                bf16x4 v1 = xv4[(size_t)s1 * 32 + l31];
                a0 += (float)v0[0]; a1 += (float)v0[1];
                a2 += (float)v0[2]; a3 += (float)v0[3];
                b0 += (float)v1[0]; b1f += (float)v1[1];
                b2f += (float)v1[2]; b3f += (float)v1[3];
            }
            if (j + 2 <= end) {
                int s0 = ent[j + half32];
                bf16x4 v0 = xv4[(size_t)s0 * 32 + l31];
                a0 += (float)v0[0]; a1 += (float)v0[1];
                a2 += (float)v0[2]; a3 += (float)v0[3];
                j += 2;
            }
            if (j < end && half32 == 0) {
                int s0 = ent[j];
                bf16x4 v0 = xv4[(size_t)s0 * 32 + l31];
                a0 += (float)v0[0]; a1 += (float)v0[1];
                a2 += (float)v0[2]; a3 += (float)v0[3];
            }
            a0 += b0; a1 += b1f; a2 += b2f; a3 += b3f;
            a0 += __shfl_xor(a0, 32); a1 += __shfl_xor(a1, 32);
            a2 += __shfl_xor(a2, 32); a3 += __shfl_xor(a3, 32);
            if (half32 == 0) {
                bf16x4 sv = xv4[(size_t)node * 32 + l31];
                a0 += (float)sv[0]; a1 += (float)sv[1];
                a2 += (float)sv[2]; a3 += (float)sv[3];
            }
        }
        if (half32 == 0) {
            bf16x4 o = {(__bf16)a0, (__bf16)a1, (__bf16)a2, (__bf16)a3};
            *reinterpret_cast<bf16x4*>(
                sh_h + q * 256 + ((l31 * 8) ^ ((q & 7) << 4))) = o;
        }
    }
    __syncthreads();

    // --- MLP on the 64-row tile: wave wv owns cols [wv*32, +32) ---
    const int wv    = wave;
    const int l15   = lane & 15;
    const int kbyte = (lane >> 4) * 16;
    const int kelem = (lane >> 4) * 8;

    // GEMM1: B-frags from global w1t (L2-resident broadcast)
    bf16x8 bf[2][4];
    #pragma unroll
    for (int nn = 0; nn < 2; ++nn) {
        int col = wv * 32 + nn * 16 + l15;
        #pragma unroll
        for (int ks = 0; ks < 4; ++ks)
            bf[nn][ks] = *reinterpret_cast<const bf16x8*>(
                w1t + col * 128 + ks * 32 + kelem);
    }

    f32x4 acc[4][2];
    #pragma unroll
    for (int m = 0; m < 4; ++m) {
        acc[m][0] = f32x4{0.f, 0.f, 0.f, 0.f};
        acc[m][1] = f32x4{0.f, 0.f, 0.f, 0.f};
        int row = m * 16 + l15;
        bf16x8 af[4];
        #pragma unroll
        for (int ks = 0; ks < 4; ++ks)
            af[ks] = *reinterpret_cast<const bf16x8*>(
                sh_h + row * 256 + ((ks * 64 + kbyte) ^ ((row & 7) << 4)));
        #pragma unroll
        for (int ks = 0; ks < 4; ++ks) {
            acc[m][0] = __builtin_amdgcn_mfma_f32_16x16x32_bf16(af[ks], bf[0][ks], acc[m][0], 0, 0, 0);
            acc[m][1] = __builtin_amdgcn_mfma_f32_16x16x32_bf16(af[ks], bf[1][ks], acc[m][1], 0, 0, 0);
        }
    }

    float bias1a = b1[wv * 32 + l15];
    float bias1b = b1[wv * 32 + 16 + l15];

    __syncthreads();   // all GEMM1 sh_h reads done

    // h1 -> sh_h (bf16, swizzled)
    #pragma unroll
    for (int m = 0; m < 4; ++m) {
        #pragma unroll
        for (int nn = 0; nn < 2; ++nn) {
            int col = wv * 32 + nn * 16 + l15;
            float bb = nn ? bias1b : bias1a;
            #pragma unroll
            for (int j = 0; j < 4; ++j) {
                int row = m * 16 + (lane >> 4) * 4 + j;
                float v = fmaxf(acc[m][nn][j] + bb, 0.f);
                *reinterpret_cast<__bf16*>(
                    sh_h + row * 256 + ((col * 2) ^ ((row & 7) << 4))) = (__bf16)v;
            }
        }
    }
    __syncthreads();

    // GEMM2: B-frags from global w2t
    #pragma unroll
    for (int nn = 0; nn < 2; ++nn) {
        int col = wv * 32 + nn * 16 + l15;
        #pragma unroll
        for (int ks = 0; ks < 4; ++ks)
            bf[nn][ks] = *reinterpret_cast<const bf16x8*>(
                w2t + col * 128 + ks * 32 + kelem);
    }

    f32x4 acc2[4][2];
    #pragma unroll
    for (int m = 0; m < 4; ++m) {
        acc2[m][0] = f32x4{0.f, 0.f, 0.f, 0.f};
        acc2[m][1] = f32x4{0.f, 0.f, 0.f, 0.f};
        int row = m * 16 + l15;
        bf16x8 af[4];
        #pragma unroll
        for (int ks = 0; ks < 4; ++ks)
            af[ks] = *reinterpret_cast<const bf16x8*>(
                sh_h + row * 256 + ((ks * 64 + kbyte) ^ ((row & 7) << 4)));
        #pragma unroll
        for (int ks = 0; ks < 4; ++ks) {
            acc2[m][0] = __builtin_amdgcn_mfma_f32_16x16x32_bf16(af[ks], bf[0][ks], acc2[m][0], 0, 0, 0);
            acc2[m][1] = __builtin_amdgcn_mfma_f32_16x16x32_bf16(af[ks], bf[1][ks], acc2[m][1], 0, 0, 0);
        }
    }

    float bias2a = b2[wv * 32 + l15];
    float bias2b = b2[wv * 32 + 16 + l15];
    const int row0 = b * 128 + half * 64;
    #pragma unroll
    for (int m = 0; m < 4; ++m) {
        #pragma unroll
        for (int nn = 0; nn < 2; ++nn) {
            int col = wv * 32 + nn * 16 + l15;
            float bb = nn ? bias2b : bias2a;
            #pragma unroll
            for (int j = 0; j < 4; ++j) {
                int row = row0 + m * 16 + (lane >> 4) * 4 + j;
                if (row < NN) out[(size_t)row * 128 + col] = acc2[m][nn][j] + bb;
            }
        }
    }
}

// ---------------------------------------------------------------------------
extern "C" void kernel_launch(void* const* d_in, const int* in_sizes, int n_in,
                              void* d_out, int out_size, void* d_ws, size_t ws_size,
                              hipStream_t stream) {
    const float* x  = (const float*)d_in[0];
    const int*   ei = (const int*)d_in[1];
    const float* W1 = (const float*)d_in[2];
    const float* b1 = (const float*)d_in[3];
    const float* W2 = (const float*)d_in[4];
    const float* b2 = (const float*)d_in[5];
    float* out = (float*)d_out;

    // ws layout: ints [gcur | bedge], then bf16 [xb | w1t | w2t]
    int* gcur  = (int*)d_ws;
    int* bedge = gcur + NBK2;
    size_t int_end = (size_t)(NBK2 + (size_t)NBK2 * CAP2) * 4;
    size_t bf_off  = (int_end + 255) & ~(size_t)255;
    __bf16* xb  = (__bf16*)((char*)d_ws + bf_off);
    __bf16* w1t = xb + (size_t)NN * D;
    __bf16* w2t = w1t + D * D;

    init_kernel<<<132, 256, 0, stream>>>(W1, W2, w1t, w2t, gcur);
    fill2x_kernel<<<NFB, 512, 0, stream>>>(x, ei, gcur, xb, bedge);
    gather_mlp_kernel<<<NBK2 * 2, 256, 0, stream>>>(xb, gcur, bedge,
                                                    w1t, w2t, b1, b2, out);
}

// Round 11
// 132.043 us; speedup vs baseline: 1.1760x; 1.1760x over previous
//
#include <hip/hip_runtime.h>

#define NN 100000
#define D  128
#define NE 1600000

#define NBK2 782          // ceil(NN/128) buckets (dst>>7), 128 nodes each
#define CAP2 2816         // slots per bucket (mean 2048, sigma ~45)
#define EPB  8192         // edges per fill block (R5/R6 measured-good)
#define NFB  196          // ceil(NE/EPB)
#define ENTCAP 2048       // per-half-bucket entry cap in gather

// prep kernel heterogeneous grid split
#define PREP_XB   12500   // blocks 0..12499: xprep (12500*256 = NN*32 chunks)
#define PREP_W    128     // blocks 12500..12627: wprep
#define PREP_Z    4       // blocks 12628..12631: zero gcur
#define PREP_GRID (PREP_XB + PREP_W + PREP_Z)

typedef __bf16 bf16x8 __attribute__((ext_vector_type(8)));
typedef __bf16 bf16x4 __attribute__((ext_vector_type(4)));
typedef float  f32x4  __attribute__((ext_vector_type(4)));

// ---------------------------------------------------------------------------
// prep: xb = bf16(x) | w1t/w2t = bf16(W^T) | gcur = 0   (independent work)
// ---------------------------------------------------------------------------
__global__ __launch_bounds__(256)
void prep_kernel(const float* __restrict__ x, const float* __restrict__ W1,
                 const float* __restrict__ W2, __bf16* __restrict__ xb,
                 __bf16* __restrict__ w1t, __bf16* __restrict__ w2t,
                 int* __restrict__ gcur) {
    const int bid = blockIdx.x;
    const int tid = threadIdx.x;
    if (bid < PREP_XB) {
        int i = bid * 256 + tid;                       // < NN*32 exactly
        float4 v = reinterpret_cast<const float4*>(x)[i];
        bf16x4 o = {(__bf16)v.x, (__bf16)v.y, (__bf16)v.z, (__bf16)v.w};
        reinterpret_cast<bf16x4*>(xb)[i] = o;
    } else if (bid < PREP_XB + PREP_W) {
        int i = (bid - PREP_XB) * 256 + tid;           // < 32768
        if (i < 16384) {
            int c = i >> 7, k = i & 127;
            w1t[i] = (__bf16)W1[k * 128 + c];
        } else {
            int j = i - 16384;
            int c = j >> 7, k = j & 127;
            w2t[j] = (__bf16)W2[k * 128 + c];
        }
    } else {
        int i = (bid - PREP_XB - PREP_W) * 256 + tid;
        if (i < NBK2) gcur[i] = 0;
    }
}

// ---------------------------------------------------------------------------
// fill2 (R5/R6 exact): LDS-binned, coalesced bucket-CSR fill, EPB=8192.
// Entry = (dst&127)<<17 | src.
// ---------------------------------------------------------------------------
__global__ __launch_bounds__(512)
void fill2_kernel(const int* __restrict__ ei, int* __restrict__ gcur,
                  int* __restrict__ bedge) {
    __shared__ int            stage[EPB];    // 32 KB
    __shared__ unsigned short bid16[EPB];    // 16 KB
    __shared__ int            lofs[NBK2];
    __shared__ int            lpos[NBK2];
    __shared__ int            gbase[NBK2];
    __shared__ int            ssum[512];
    __shared__ int            tot;

    const int tid = threadIdx.x;
    const int e0  = blockIdx.x * EPB;

    for (int b = tid; b < NBK2; b += 512) lpos[b] = 0;
    __syncthreads();

    int eb[16], epk[16];
    #pragma unroll 16
    for (int k = 0; k < 16; ++k) {
        int e = e0 + k * 512 + tid;
        eb[k] = -1;
        if (e < NE) {
            int s = ei[e];
            int d = ei[NE + e];
            if ((unsigned)s < NN && (unsigned)d < NN) {
                eb[k]  = d >> 7;
                epk[k] = ((d & 127) << 17) | s;
                atomicAdd(&lpos[eb[k]], 1);
            }
        }
    }
    __syncthreads();

    int t2 = tid * 2;
    int c0 = (t2 < NBK2) ? lpos[t2] : 0;
    int c1 = (t2 + 1 < NBK2) ? lpos[t2 + 1] : 0;
    ssum[tid] = c0 + c1;
    __syncthreads();
    for (int off = 1; off < 512; off <<= 1) {
        int v = (tid >= off) ? ssum[tid - off] : 0;
        __syncthreads();
        ssum[tid] += v;
        __syncthreads();
    }
    int excl = ssum[tid] - (c0 + c1);
    if (t2 < NBK2) {
        lofs[t2] = excl;
        lpos[t2] = excl;
        if (c0) gbase[t2] = atomicAdd(&gcur[t2], c0);
    }
    if (t2 + 1 < NBK2) {
        lofs[t2 + 1] = excl + c0;
        lpos[t2 + 1] = excl + c0;
        if (c1) gbase[t2 + 1] = atomicAdd(&gcur[t2 + 1], c1);
    }
    if (tid == 511) tot = ssum[511];
    __syncthreads();

    #pragma unroll 16
    for (int k = 0; k < 16; ++k) {
        if (eb[k] >= 0) {
            int r = atomicAdd(&lpos[eb[k]], 1);
            stage[r] = epk[k];
            bid16[r] = (unsigned short)eb[k];
        }
    }
    __syncthreads();

    int T = tot;
    for (int i = tid; i < T; i += 512) {
        int b   = bid16[i];
        int pos = gbase[b] + (i - lofs[b]);
        if (pos < CAP2) bedge[b * CAP2 + pos] = stage[i];
    }
}

// ---------------------------------------------------------------------------
// gather3 (exact): 2 blocks per bucket, 256 threads, paired loads.
// ---------------------------------------------------------------------------
__global__ __launch_bounds__(256)
void gather3_kernel(const __bf16* __restrict__ xb, const int* __restrict__ gcur,
                    const int* __restrict__ bedge, __bf16* __restrict__ hb) {
    __shared__ int ent[ENTCAP];
    __shared__ int c64[64], ofs[65], cur[64], scn[64];

    const int b    = blockIdx.x >> 1;
    const int half = blockIdx.x & 1;
    const int tid  = threadIdx.x;

    int cnt = gcur[b]; if (cnt > CAP2) cnt = CAP2;
    const int base = b * CAP2;

    if (tid < 64) c64[tid] = 0;
    __syncthreads();

    for (int i = tid; i < cnt; i += 256) {
        int v  = bedge[base + i];
        int dl = v >> 17;
        if ((dl >> 6) == half) atomicAdd(&c64[dl & 63], 1);
    }
    __syncthreads();

    if (tid < 64) scn[tid] = c64[tid];
    __syncthreads();
    #pragma unroll
    for (int off = 1; off < 64; off <<= 1) {
        int v = (tid >= off && tid < 64) ? scn[tid - off] : 0;
        __syncthreads();
        if (tid < 64) scn[tid] += v;
        __syncthreads();
    }
    if (tid < 64) {
        ofs[tid + 1] = scn[tid];
        if (tid == 0) ofs[0] = 0;
        cur[tid] = scn[tid] - c64[tid];
    }
    __syncthreads();

    for (int i = tid; i < cnt; i += 256) {
        int v  = bedge[base + i];
        int dl = v >> 17;
        if ((dl >> 6) == half) {
            int r = atomicAdd(&cur[dl & 63], 1);
            if (r < ENTCAP) ent[r] = v & 0x1FFFF;
        }
    }
    __syncthreads();

    const int wave   = tid >> 6;
    const int lane   = tid & 63;
    const int half32 = lane >> 5;
    const int l31    = lane & 31;
    const bf16x4* xv4 = reinterpret_cast<const bf16x4*>(xb);

    for (int q = wave; q < 64; q += 4) {
        int node = b * 128 + half * 64 + q;
        if (node >= NN) continue;
        int beg = ofs[q], end = ofs[q + 1];
        if (beg > ENTCAP) beg = ENTCAP;
        if (end > ENTCAP) end = ENTCAP;

        float a0 = 0.f, a1 = 0.f, a2 = 0.f, a3 = 0.f;
        float b0 = 0.f, b1 = 0.f, b2f = 0.f, b3 = 0.f;
        int j = beg;
        for (; j + 4 <= end; j += 4) {
            int s0 = ent[j + half32];
            int s1 = ent[j + 2 + half32];
            bf16x4 v0 = xv4[(size_t)s0 * 32 + l31];
            bf16x4 v1 = xv4[(size_t)s1 * 32 + l31];
            a0 += (float)v0[0]; a1 += (float)v0[1];
            a2 += (float)v0[2]; a3 += (float)v0[3];
            b0 += (float)v1[0]; b1 += (float)v1[1];
            b2f += (float)v1[2]; b3 += (float)v1[3];
        }
        if (j + 2 <= end) {
            int s0 = ent[j + half32];
            bf16x4 v0 = xv4[(size_t)s0 * 32 + l31];
            a0 += (float)v0[0]; a1 += (float)v0[1];
            a2 += (float)v0[2]; a3 += (float)v0[3];
            j += 2;
        }
        if (j < end && half32 == 0) {
            int s0 = ent[j];
            bf16x4 v0 = xv4[(size_t)s0 * 32 + l31];
            a0 += (float)v0[0]; a1 += (float)v0[1];
            a2 += (float)v0[2]; a3 += (float)v0[3];
        }
        a0 += b0; a1 += b1; a2 += b2f; a3 += b3;
        a0 += __shfl_xor(a0, 32); a1 += __shfl_xor(a1, 32);
        a2 += __shfl_xor(a2, 32); a3 += __shfl_xor(a3, 32);

        if (half32 == 0) {
            bf16x4 sv = xv4[(size_t)node * 32 + l31];
            bf16x4 o = {(__bf16)(a0 + (float)sv[0]), (__bf16)(a1 + (float)sv[1]),
                        (__bf16)(a2 + (float)sv[2]), (__bf16)(a3 + (float)sv[3])};
            reinterpret_cast<bf16x4*>(hb)[(size_t)node * 32 + l31] = o;
        }
    }
}

// ---------------------------------------------------------------------------
// mlp_mfma (R6 exact): 64 rows/block, 256 thr / 4 waves; h + W^T in swizzled
// LDS (W1 then W2). out = relu(h@W1+b1)@W2+b2
// ---------------------------------------------------------------------------
__global__ __launch_bounds__(256)
void mlp_mfma_kernel(const __bf16* __restrict__ hb,
                     const __bf16* __restrict__ w1t,
                     const __bf16* __restrict__ w2t,
                     const float* __restrict__ b1,
                     const float* __restrict__ b2,
                     float* __restrict__ out) {
    __shared__ __align__(16) unsigned char sh_h[64 * 256];    // 16 KB
    __shared__ __align__(16) unsigned char sh_w[128 * 256];   // 32 KB

    const int tid   = threadIdx.x;
    const int wv    = tid >> 6;
    const int lane  = tid & 63;
    const int l15   = lane & 15;
    const int kbyte = (lane >> 4) * 16;
    const int row0  = blockIdx.x * 64;

    for (int c = tid; c < 1024; c += 256) {
        int r = c >> 4, s = c & 15;
        int grow = row0 + r;
        int4 val = make_int4(0, 0, 0, 0);
        if (grow < NN) val = *reinterpret_cast<const int4*>(hb + (size_t)grow * 128 + s * 8);
        *reinterpret_cast<int4*>(sh_h + r * 256 + ((s * 16) ^ ((r & 7) << 4))) = val;
    }
    for (int c = tid; c < 2048; c += 256) {
        int r = c >> 4, s = c & 15;
        int4 val = *reinterpret_cast<const int4*>(w1t + r * 128 + s * 8);
        *reinterpret_cast<int4*>(sh_w + r * 256 + ((s * 16) ^ ((r & 7) << 4))) = val;
    }
    __syncthreads();

    bf16x8 bf1[2][4];
    #pragma unroll
    for (int nn = 0; nn < 2; ++nn) {
        int col = wv * 32 + nn * 16 + l15;
        #pragma unroll
        for (int ks = 0; ks < 4; ++ks)
            bf1[nn][ks] = *reinterpret_cast<const bf16x8*>(
                sh_w + col * 256 + ((ks * 64 + kbyte) ^ ((col & 7) << 4)));
    }

    f32x4 acc[4][2];
    #pragma unroll
    for (int m = 0; m < 4; ++m) {
        acc[m][0] = f32x4{0.f, 0.f, 0.f, 0.f};
        acc[m][1] = f32x4{0.f, 0.f, 0.f, 0.f};
        int row = m * 16 + l15;
        bf16x8 af[4];
        #pragma unroll
        for (int ks = 0; ks < 4; ++ks)
            af[ks] = *reinterpret_cast<const bf16x8*>(
                sh_h + row * 256 + ((ks * 64 + kbyte) ^ ((row & 7) << 4)));
        #pragma unroll
        for (int ks = 0; ks < 4; ++ks) {
            acc[m][0] = __builtin_amdgcn_mfma_f32_16x16x32_bf16(af[ks], bf1[0][ks], acc[m][0], 0, 0, 0);
            acc[m][1] = __builtin_amdgcn_mfma_f32_16x16x32_bf16(af[ks], bf1[1][ks], acc[m][1], 0, 0, 0);
        }
    }

    float bias1a = b1[wv * 32 + l15];
    float bias1b = b1[wv * 32 + 16 + l15];

    __syncthreads();

    #pragma unroll
    for (int m = 0; m < 4; ++m) {
        #pragma unroll
        for (int nn = 0; nn < 2; ++nn) {
            int col = wv * 32 + nn * 16 + l15;
            float bb = nn ? bias1b : bias1a;
            #pragma unroll
            for (int j = 0; j < 4; ++j) {
                int row = m * 16 + (lane >> 4) * 4 + j;
                float v = fmaxf(acc[m][nn][j] + bb, 0.f);
                *reinterpret_cast<__bf16*>(
                    sh_h + row * 256 + ((col * 2) ^ ((row & 7) << 4))) = (__bf16)v;
            }
        }
    }
    for (int c = tid; c < 2048; c += 256) {
        int r = c >> 4, s = c & 15;
        int4 val = *reinterpret_cast<const int4*>(w2t + r * 128 + s * 8);
        *reinterpret_cast<int4*>(sh_w + r * 256 + ((s * 16) ^ ((r & 7) << 4))) = val;
    }
    __syncthreads();

    bf16x8 bf2[2][4];
    #pragma unroll
    for (int nn = 0; nn < 2; ++nn) {
        int col = wv * 32 + nn * 16 + l15;
        #pragma unroll
        for (int ks = 0; ks < 4; ++ks)
            bf2[nn][ks] = *reinterpret_cast<const bf16x8*>(
                sh_w + col * 256 + ((ks * 64 + kbyte) ^ ((col & 7) << 4)));
    }

    f32x4 acc2[4][2];
    #pragma unroll
    for (int m = 0; m < 4; ++m) {
        acc2[m][0] = f32x4{0.f, 0.f, 0.f, 0.f};
        acc2[m][1] = f32x4{0.f, 0.f, 0.f, 0.f};
        int row = m * 16 + l15;
        bf16x8 af[4];
        #pragma unroll
        for (int ks = 0; ks < 4; ++ks)
            af[ks] = *reinterpret_cast<const bf16x8*>(
                sh_h + row * 256 + ((ks * 64 + kbyte) ^ ((row & 7) << 4)));
        #pragma unroll
        for (int ks = 0; ks < 4; ++ks) {
            acc2[m][0] = __builtin_amdgcn_mfma_f32_16x16x32_bf16(af[ks], bf2[0][ks], acc2[m][0], 0, 0, 0);
            acc2[m][1] = __builtin_amdgcn_mfma_f32_16x16x32_bf16(af[ks], bf2[1][ks], acc2[m][1], 0, 0, 0);
        }
    }

    float bias2a = b2[wv * 32 + l15];
    float bias2b = b2[wv * 32 + 16 + l15];
    #pragma unroll
    for (int m = 0; m < 4; ++m) {
        #pragma unroll
        for (int nn = 0; nn < 2; ++nn) {
            int col = wv * 32 + nn * 16 + l15;
            float bb = nn ? bias2b : bias2a;
            #pragma unroll
            for (int j = 0; j < 4; ++j) {
                int row = row0 + m * 16 + (lane >> 4) * 4 + j;
                if (row < NN) out[(size_t)row * 128 + col] = acc2[m][nn][j] + bb;
            }
        }
    }
}

// ---------------------------------------------------------------------------
extern "C" void kernel_launch(void* const* d_in, const int* in_sizes, int n_in,
                              void* d_out, int out_size, void* d_ws, size_t ws_size,
                              hipStream_t stream) {
    const float* x  = (const float*)d_in[0];
    const int*   ei = (const int*)d_in[1];
    const float* W1 = (const float*)d_in[2];
    const float* b1 = (const float*)d_in[3];
    const float* W2 = (const float*)d_in[4];
    const float* b2 = (const float*)d_in[5];
    float* out = (float*)d_out;

    // ws layout: ints [gcur | bedge], then bf16 [xb | hb | w1t | w2t]
    int* gcur  = (int*)d_ws;
    int* bedge = gcur + NBK2;
    size_t int_end = (size_t)(NBK2 + (size_t)NBK2 * CAP2) * 4;
    size_t bf_off  = (int_end + 255) & ~(size_t)255;
    __bf16* xb  = (__bf16*)((char*)d_ws + bf_off);
    __bf16* hb  = xb + (size_t)NN * D;
    __bf16* w1t = hb + (size_t)NN * D;
    __bf16* w2t = w1t + D * D;

    prep_kernel<<<PREP_GRID, 256, 0, stream>>>(x, W1, W2, xb, w1t, w2t, gcur);
    fill2_kernel<<<NFB, 512, 0, stream>>>(ei, gcur, bedge);
    gather3_kernel<<<NBK2 * 2, 256, 0, stream>>>(xb, gcur, bedge, hb);
    mlp_mfma_kernel<<<(NN + 63) / 64, 256, 0, stream>>>(hb, w1t, w2t, b1, b2, out);
}